// Round 2
// baseline (1080.370 us; speedup 1.0000x reference)
//
#include <hip/hip_runtime.h>
#include <hip/hip_bf16.h>

typedef __hip_bfloat16 bf16;
typedef __attribute__((ext_vector_type(8))) short bfrag8;   // 8 bf16 = 4 VGPRs (MFMA A/B frag)
typedef __attribute__((ext_vector_type(4))) float floatx4;  // MFMA C/D frag

#define BM 64
#define BN 64
#define BKK 64
#define PAD 8   // LDS row stride 72 shorts = 144B; frag b128 reads land 2-way (free per m136)

__device__ inline float bf2f_bits(unsigned short u) {
    unsigned int b = (unsigned int)u << 16;
    float f; __builtin_memcpy(&f, &b, 4); return f;
}
__device__ inline unsigned short f2bf_bits(float f) {
    union { __hip_bfloat16 h; unsigned short u; } c;
    c.h = __float2bfloat16(f);
    return c.u;
}

// fp32 -> bf16, 8 elements per thread. n8 = element_count / 8.
__global__ __launch_bounds__(256)
void f32_to_bf16(const float* __restrict__ src, bf16* __restrict__ dst, int n8)
{
    int i = blockIdx.x * 256 + threadIdx.x;
    if (i >= n8) return;
    const float4* s = (const float4*)src;
    float4 a = s[i * 2], b = s[i * 2 + 1];
    union { uint4 u; unsigned short h[8]; } o;
    o.h[0] = f2bf_bits(a.x); o.h[1] = f2bf_bits(a.y);
    o.h[2] = f2bf_bits(a.z); o.h[3] = f2bf_bits(a.w);
    o.h[4] = f2bf_bits(b.x); o.h[5] = f2bf_bits(b.y);
    o.h[6] = f2bf_bits(b.z); o.h[7] = f2bf_bits(b.w);
    ((uint4*)dst)[i] = o.u;
}

// C[M,N] = (op(A) * B + bias[row]) * scale.  A,B bf16; accum fp32;
// C is bf16 (OUTF32=false) or fp32 (OUTF32=true). bias is fp32.
// ATRANS=false: A is [M,K] (k contiguous); ATRANS=true: A is [K,M] (m contiguous).
// B is [K,N] (n contiguous). M,N multiples of 64; K multiple of 64.
template<bool ATRANS, bool BIAS, bool OUTF32>
__global__ __launch_bounds__(256)
void gemm_bf16(const bf16* __restrict__ Ag, long sAb, int lda,
               const bf16* __restrict__ Bg, long sBb, int ldb,
               void* __restrict__ Cg, long sCb, int ldc,
               const float* __restrict__ bias, float scale, int K)
{
    __shared__ unsigned short As[BM][BKK + PAD];  // [m][k]
    __shared__ unsigned short Bs[BN][BKK + PAD];  // [n][k]

    const int bz = blockIdx.z;
    const bf16* A  = Ag + (size_t)bz * sAb;
    const bf16* Bp = Bg + (size_t)bz * sBb;
    const int bm = blockIdx.y * BM;
    const int bn = blockIdx.x * BN;
    const int t    = threadIdx.x;
    const int wave = t >> 6;
    const int lane = t & 63;
    const int qrow = lane & 15;
    const int quad = lane >> 4;

    floatx4 acc[4] = {};

    for (int k0 = 0; k0 < K; k0 += BKK) {
        if (!ATRANS) {
            #pragma unroll
            for (int i = 0; i < 2; ++i) {
                int idx = t + i * 256;
                int m  = idx >> 3;
                int kk = (idx & 7) * 8;
                uint4 v = *(const uint4*)(A + (size_t)(bm + m) * lda + (k0 + kk));
                *(uint4*)&As[m][kk] = v;
            }
        } else {
            #pragma unroll
            for (int i = 0; i < 2; ++i) {
                int idx = t + i * 256;
                int k  = idx >> 3;
                int mm = (idx & 7) * 8;
                union { uint4 u; unsigned short s[8]; } cv;
                cv.u = *(const uint4*)(A + (size_t)(k0 + k) * lda + (bm + mm));
                #pragma unroll
                for (int j = 0; j < 8; ++j) {       // stagger scalar writes across banks
                    int jj = (j + t) & 7;
                    As[mm + jj][k] = cv.s[jj];
                }
            }
        }
        #pragma unroll
        for (int i = 0; i < 2; ++i) {
            int idx = t + i * 256;
            int k  = idx >> 3;
            int nn = (idx & 7) * 8;
            union { uint4 u; unsigned short s[8]; } cv;
            cv.u = *(const uint4*)(Bp + (size_t)(k0 + k) * ldb + (bn + nn));
            #pragma unroll
            for (int j = 0; j < 8; ++j) {
                int jj = (j + t) & 7;
                Bs[nn + jj][k] = cv.s[jj];
            }
        }
        __syncthreads();

        #pragma unroll
        for (int ks = 0; ks < BKK; ks += 32) {
            bfrag8 af = *(const bfrag8*)&As[wave * 16 + qrow][ks + quad * 8];
            #pragma unroll
            for (int nb = 0; nb < 4; ++nb) {
                bfrag8 bf = *(const bfrag8*)&Bs[nb * 16 + qrow][ks + quad * 8];
                acc[nb] = __builtin_amdgcn_mfma_f32_16x16x32_bf16(af, bf, acc[nb], 0, 0, 0);
            }
        }
        __syncthreads();
    }

    // D layout: col=lane&15, row=quad*4+reg  [m89-verified]
    #pragma unroll
    for (int nb = 0; nb < 4; ++nb) {
        #pragma unroll
        for (int r = 0; r < 4; ++r) {
            int row = bm + wave * 16 + quad * 4 + r;
            int col = bn + nb * 16 + qrow;
            float v = acc[nb][r];
            if (BIAS) v += bias[row];
            v *= scale;
            if (OUTF32) {
                ((float*)Cg + (size_t)bz * sCb)[(size_t)row * ldc + col] = v;
            } else {
                ((bf16*)Cg + (size_t)bz * sCb)[(size_t)row * ldc + col] = __float2bfloat16(v);
            }
        }
    }
}

// One wave per row of S[rows, 2048]; softmax over columns, in place, bf16.
__global__ __launch_bounds__(256)
void softmax_rows(bf16* __restrict__ S, int Lr)
{
    int row  = blockIdx.x * 4 + (threadIdx.x >> 6);
    int lane = threadIdx.x & 63;
    bf16* p = S + (size_t)row * Lr;

    float v[32];
    #pragma unroll
    for (int i = 0; i < 4; ++i) {
        union { uint4 u; unsigned short s[8]; } cv;
        cv.u = *(const uint4*)(p + i * 512 + lane * 8);
        #pragma unroll
        for (int j = 0; j < 8; ++j) v[i * 8 + j] = bf2f_bits(cv.s[j]);
    }
    float mx = v[0];
    #pragma unroll
    for (int i = 1; i < 32; ++i) mx = fmaxf(mx, v[i]);
    #pragma unroll
    for (int off = 32; off >= 1; off >>= 1) mx = fmaxf(mx, __shfl_xor(mx, off, 64));

    float sum = 0.f;
    #pragma unroll
    for (int i = 0; i < 32; ++i) { v[i] = __expf(v[i] - mx); sum += v[i]; }
    #pragma unroll
    for (int off = 32; off >= 1; off >>= 1) sum += __shfl_xor(sum, off, 64);
    float inv = 1.0f / sum;

    #pragma unroll
    for (int i = 0; i < 4; ++i) {
        union { uint4 u; unsigned short s[8]; } cv;
        #pragma unroll
        for (int j = 0; j < 8; ++j) cv.s[j] = f2bf_bits(v[i * 8 + j] * inv);
        *(uint4*)(p + i * 512 + lane * 8) = cv.u;
    }
}

extern "C" void kernel_launch(void* const* d_in, const int* in_sizes, int n_in,
                              void* d_out, int out_size, void* d_ws, size_t ws_size,
                              hipStream_t stream)
{
    const int Bb = 8, Cc = 1024, Ll = 2048, Aa = 128;
    const float* x  = (const float*)d_in[0];
    const float* Wk = (const float*)d_in[1];
    const float* bk = (const float*)d_in[2];
    const float* Wq = (const float*)d_in[3];
    const float* bq = (const float*)d_in[4];
    const float* Wp = (const float*)d_in[5];
    const float* bp = (const float*)d_in[6];
    float* out = (float*)d_out;

    const float kscale = 2.0f / (float)Ll;   // softmax(values/(L/2)) folded into keys
    dim3 blk(256, 1, 1);

    const size_t nX  = (size_t)Bb * Cc * Ll;   // 16,777,216
    const size_t nWk = (size_t)Aa * Cc;        // 131,072
    const size_t nWp = (size_t)Cc * Cc;        // 1,048,576
    const size_t nKs = (size_t)Bb * Aa * Ll;   // 2,097,152
    const size_t nS  = (size_t)Bb * Ll * Ll;   // 33,554,432

    const size_t fullBytes = 2 * (nX + 2 * nWk + nWp + 2 * nKs + nS + nX); // ~139 MiB

    if (ws_size >= fullBytes) {
        // ---------------- full-batch path ----------------
        bf16* xb  = (bf16*)d_ws;
        bf16* Wkb = xb  + nX;
        bf16* Wqb = Wkb + nWk;
        bf16* Wpb = Wqb + nWk;
        bf16* Ks  = Wpb + nWp;
        bf16* Qs  = Ks  + nKs;
        bf16* S   = Qs  + nKs;
        bf16* O1  = S   + nS;

        f32_to_bf16<<<dim3(nX / 8 / 256), blk, 0, stream>>>(x, xb, nX / 8);
        f32_to_bf16<<<dim3(nWk / 8 / 256), blk, 0, stream>>>(Wk, Wkb, nWk / 8);
        f32_to_bf16<<<dim3(nWk / 8 / 256), blk, 0, stream>>>(Wq, Wqb, nWk / 8);
        f32_to_bf16<<<dim3(nWp / 8 / 256), blk, 0, stream>>>(Wp, Wpb, nWp / 8);

        gemm_bf16<false, true, false><<<dim3(Ll/BN, Aa/BM, Bb), blk, 0, stream>>>(
            Wkb, 0, Cc,  xb, (long)Cc*Ll, Ll,  Ks, (long)Aa*Ll, Ll,  bk, kscale, Cc);
        gemm_bf16<false, true, false><<<dim3(Ll/BN, Aa/BM, Bb), blk, 0, stream>>>(
            Wqb, 0, Cc,  xb, (long)Cc*Ll, Ll,  Qs, (long)Aa*Ll, Ll,  bq, 1.0f, Cc);
        gemm_bf16<true, false, false><<<dim3(Ll/BN, Ll/BM, Bb), blk, 0, stream>>>(
            Ks, (long)Aa*Ll, Ll,  Qs, (long)Aa*Ll, Ll,  S, (long)Ll*Ll, Ll,  nullptr, 1.0f, Aa);
        softmax_rows<<<dim3(Bb*Ll/4), blk, 0, stream>>>(S, Ll);
        gemm_bf16<false, false, false><<<dim3(Ll/BN, Cc/BM, Bb), blk, 0, stream>>>(
            xb, (long)Cc*Ll, Ll,  S, (long)Ll*Ll, Ll,  O1, (long)Cc*Ll, Ll,  nullptr, 1.0f, Ll);
        gemm_bf16<false, true, true><<<dim3(Ll/BN, Cc/BM, Bb), blk, 0, stream>>>(
            Wpb, 0, Cc,  O1, (long)Cc*Ll, Ll,  out, (long)Cc*Ll, Ll,  bp, 1.0f, Cc);
    } else {
        // ---------------- per-batch path (~19.5 MiB ws) ----------------
        bf16* Wkb = (bf16*)d_ws;
        bf16* Wqb = Wkb + nWk;
        bf16* Wpb = Wqb + nWk;
        bf16* xbb = Wpb + nWp;                       // [C,L] one batch
        bf16* Ksb = xbb + (size_t)Cc * Ll;           // [A,L]
        bf16* Qsb = Ksb + (size_t)Aa * Ll;
        bf16* Sb  = Qsb + (size_t)Aa * Ll;           // [L,L]
        bf16* O1b = Sb  + (size_t)Ll * Ll;           // [C,L]

        f32_to_bf16<<<dim3(nWk / 8 / 256), blk, 0, stream>>>(Wk, Wkb, nWk / 8);
        f32_to_bf16<<<dim3(nWk / 8 / 256), blk, 0, stream>>>(Wq, Wqb, nWk / 8);
        f32_to_bf16<<<dim3(nWp / 8 / 256), blk, 0, stream>>>(Wp, Wpb, nWp / 8);

        const size_t nXb = (size_t)Cc * Ll;
        for (int b = 0; b < Bb; ++b) {
            const float* xB = x + (size_t)b * nXb;
            f32_to_bf16<<<dim3(nXb / 8 / 256), blk, 0, stream>>>(xB, xbb, nXb / 8);
            gemm_bf16<false, true, false><<<dim3(Ll/BN, Aa/BM, 1), blk, 0, stream>>>(
                Wkb, 0, Cc,  xbb, 0, Ll,  Ksb, 0, Ll,  bk, kscale, Cc);
            gemm_bf16<false, true, false><<<dim3(Ll/BN, Aa/BM, 1), blk, 0, stream>>>(
                Wqb, 0, Cc,  xbb, 0, Ll,  Qsb, 0, Ll,  bq, 1.0f, Cc);
            gemm_bf16<true, false, false><<<dim3(Ll/BN, Ll/BM, 1), blk, 0, stream>>>(
                Ksb, 0, Ll,  Qsb, 0, Ll,  Sb, 0, Ll,  nullptr, 1.0f, Aa);
            softmax_rows<<<dim3(Ll/4), blk, 0, stream>>>(Sb, Ll);
            gemm_bf16<false, false, false><<<dim3(Ll/BN, Cc/BM, 1), blk, 0, stream>>>(
                xbb, 0, Ll,  Sb, 0, Ll,  O1b, 0, Ll,  nullptr, 1.0f, Ll);
            gemm_bf16<false, true, true><<<dim3(Ll/BN, Cc/BM, 1), blk, 0, stream>>>(
                Wpb, 0, Cc,  O1b, 0, Ll,  out + (size_t)b * nXb, 0, Ll,  bp, 1.0f, Cc);
        }
    }
}

// Round 3
// 368.540 us; speedup vs baseline: 2.9315x; 2.9315x over previous
//
#include <hip/hip_runtime.h>
#include <hip/hip_bf16.h>

typedef __hip_bfloat16 bf16;
typedef __attribute__((ext_vector_type(8))) short bfrag8;   // 8 bf16 = 4 VGPRs
typedef __attribute__((ext_vector_type(4))) float floatx4;  // MFMA C/D frag

__device__ inline float bf2f_bits(unsigned short u) {
    unsigned int b = (unsigned int)u << 16;
    float f; __builtin_memcpy(&f, &b, 4); return f;
}
__device__ inline unsigned short f2bf_bits(float f) {
    union { __hip_bfloat16 h; unsigned short u; } c;
    c.h = __float2bfloat16(f);
    return c.u;
}

// async global->LDS, 16B per lane. LDS dest MUST be wave-uniform base + lane*16.
__device__ __forceinline__ void async_copy16(const bf16* g, unsigned short* lds) {
    __builtin_amdgcn_global_load_lds(
        (const __attribute__((address_space(1))) unsigned int*)g,
        (__attribute__((address_space(3))) unsigned int*)lds, 16, 0, 0);
}

// ---------------------------------------------------------------------------
// Uniform GEMM: out[rowA][rowB] = sum_k A[rowA][k] * B[rowB][k]
// Both operands K-contiguous. 128x128 tile, BK=64, 4 waves, 4x4 acc each.
// global_load_lds(16B) staging with chunk-XOR swizzle (p ^= row&7) applied to
// the GLOBAL source address; frag ds_read_b128 applies the same swizzle.
// BIASMODE: 0 none; 1 col: v = v*scl[col] + b2[col]; 2 row: v += scl[row].
// ---------------------------------------------------------------------------
template<int BIASMODE, bool OUTF32>
__global__ __launch_bounds__(256)
void gemm128(const bf16* __restrict__ Ag, long sAb, int lda,
             const bf16* __restrict__ Bg, long sBb, int ldb,
             void* __restrict__ Cg, long sCb, int ldc,
             const float* __restrict__ scl, const float* __restrict__ b2,
             int K)
{
    __shared__ unsigned short As[128 * 64];
    __shared__ unsigned short Bs[128 * 64];

    const int bz = blockIdx.z;
    const bf16* A  = Ag + (size_t)bz * sAb + (size_t)blockIdx.y * 128 * lda;
    const bf16* Bp = Bg + (size_t)bz * sBb + (size_t)blockIdx.x * 128 * ldb;
    const int t    = threadIdx.x;
    const int wave = t >> 6;
    const int lane = t & 63;
    const int qrow = lane & 15;
    const int quad = lane >> 4;
    const int wr = (wave >> 1) * 64;   // wave's 64x64 quadrant
    const int wc = (wave & 1) * 64;

    floatx4 acc[4][4] = {};

    for (int k0 = 0; k0 < K; k0 += 64) {
        #pragma unroll
        for (int j = 0; j < 4; ++j) {           // A tile: 1024 chunks of 16B
            int c = j * 256 + t;
            int r = c >> 3, p = c & 7;
            int g = p ^ (r & 7);                // XOR swizzle on source
            async_copy16(A + (size_t)r * lda + k0 + g * 8, &As[c * 8]);
        }
        #pragma unroll
        for (int j = 0; j < 4; ++j) {           // B tile
            int c = j * 256 + t;
            int r = c >> 3, p = c & 7;
            int g = p ^ (r & 7);
            async_copy16(Bp + (size_t)r * ldb + k0 + g * 8, &Bs[c * 8]);
        }
        __syncthreads();                        // drains vmcnt (global_load_lds)

        #pragma unroll
        for (int ks = 0; ks < 2; ++ks) {
            bfrag8 af[4], bfv[4];
            #pragma unroll
            for (int mi = 0; mi < 4; ++mi) {
                int row = wr + mi * 16 + qrow;
                int ck  = ks * 4 + quad;
                af[mi] = *(const bfrag8*)&As[row * 64 + ((ck ^ (row & 7)) * 8)];
            }
            #pragma unroll
            for (int ni = 0; ni < 4; ++ni) {
                int row = wc + ni * 16 + qrow;
                int ck  = ks * 4 + quad;
                bfv[ni] = *(const bfrag8*)&Bs[row * 64 + ((ck ^ (row & 7)) * 8)];
            }
            #pragma unroll
            for (int mi = 0; mi < 4; ++mi)
                #pragma unroll
                for (int ni = 0; ni < 4; ++ni)
                    acc[mi][ni] = __builtin_amdgcn_mfma_f32_16x16x32_bf16(
                        af[mi], bfv[ni], acc[mi][ni], 0, 0, 0);
        }
        __syncthreads();
    }

    // epilogue: D layout col=lane&15, row=quad*4+reg  [m89-verified]
    const int bmr = blockIdx.y * 128 + wr;
    const int bnc = blockIdx.x * 128 + wc;
    #pragma unroll
    for (int mi = 0; mi < 4; ++mi) {
        #pragma unroll
        for (int ni = 0; ni < 4; ++ni) {
            int col = bnc + ni * 16 + qrow;
            #pragma unroll
            for (int r = 0; r < 4; ++r) {
                int row = bmr + mi * 16 + quad * 4 + r;
                float v = acc[mi][ni][r];
                if (BIASMODE == 1) v = v * scl[col] + b2[col];
                if (BIASMODE == 2) v += scl[row];
                if (OUTF32)
                    ((float*)Cg + (size_t)bz * sCb)[(size_t)row * ldc + col] = v;
                else
                    ((bf16*)Cg + (size_t)bz * sCb)[(size_t)row * ldc + col] = __float2bfloat16(v);
            }
        }
    }
}

// fp32 -> bf16, 8 elements per thread.
__global__ __launch_bounds__(256)
void f32_to_bf16(const float* __restrict__ src, bf16* __restrict__ dst, int n8)
{
    int i = blockIdx.x * 256 + threadIdx.x;
    if (i >= n8) return;
    const float4* s = (const float4*)src;
    float4 a = s[i * 2], b = s[i * 2 + 1];
    union { uint4 u; unsigned short h[8]; } o;
    o.h[0] = f2bf_bits(a.x); o.h[1] = f2bf_bits(a.y);
    o.h[2] = f2bf_bits(a.z); o.h[3] = f2bf_bits(a.w);
    o.h[4] = f2bf_bits(b.x); o.h[5] = f2bf_bits(b.y);
    o.h[6] = f2bf_bits(b.z); o.h[7] = f2bf_bits(b.w);
    ((uint4*)dst)[i] = o.u;
}

// x fp32 [C,L] -> xb bf16 [C,L] + xt bf16 [L,C]   (64x64 LDS tile transpose)
__global__ __launch_bounds__(256)
void conv_x(const float* __restrict__ x, bf16* __restrict__ xb, bf16* __restrict__ xt)
{
    const int b = blockIdx.z;
    const int l0 = blockIdx.x * 64, c0 = blockIdx.y * 64;
    const float* xp = x + (size_t)b * 1024 * 2048;
    bf16* xbp = xb + (size_t)b * 1024 * 2048;
    bf16* xtp = xt + (size_t)b * 2048 * 1024;
    __shared__ unsigned short tile[64][65];
    const int t = threadIdx.x;
    const int tr = t >> 4, tc4 = (t & 15) * 4;
    #pragma unroll
    for (int i = 0; i < 4; ++i) {
        int r = i * 16 + tr;   // local c
        float4 v = *(const float4*)(xp + (size_t)(c0 + r) * 2048 + l0 + tc4);
        union { uint2 u; unsigned short h[4]; } o;
        o.h[0] = f2bf_bits(v.x); o.h[1] = f2bf_bits(v.y);
        o.h[2] = f2bf_bits(v.z); o.h[3] = f2bf_bits(v.w);
        *(uint2*)(xbp + (size_t)(c0 + r) * 2048 + l0 + tc4) = o.u;
        tile[r][tc4] = o.h[0]; tile[r][tc4 + 1] = o.h[1];
        tile[r][tc4 + 2] = o.h[2]; tile[r][tc4 + 3] = o.h[3];
    }
    __syncthreads();
    #pragma unroll
    for (int i = 0; i < 4; ++i) {
        int lrow = i * 16 + tr;   // local l
        union { uint2 u; unsigned short h[4]; } o;
        #pragma unroll
        for (int j = 0; j < 4; ++j) o.h[j] = tile[tc4 + j][lrow];
        *(uint2*)(xtp + (size_t)(l0 + lrow) * 1024 + c0 + tc4) = o.u;
    }
}

// col-bias prep: scl[i] = (i<128 ? kscale : 1); b2[i] = bias_i * scl[i]
__global__ void prep_bias(const float* __restrict__ bk, const float* __restrict__ bq,
                          float* __restrict__ scl, float* __restrict__ b2, float kscale)
{
    int t = threadIdx.x;   // 256
    float s = (t < 128) ? kscale : 1.0f;
    scl[t] = s;
    b2[t] = ((t < 128) ? bk[t] : bq[t - 128]) * s;
}

// St[m][l]: softmax over m (columns of St). P1: Z[l] += sum_m exp(St[m][l]).
// Logits are ~±0.06 (kscale folded) so max-subtraction is unnecessary.
__global__ __launch_bounds__(256)
void softmax_sum(const bf16* __restrict__ St, float* __restrict__ Z)
{
    const int b = blockIdx.z, mp = blockIdx.y, cb = blockIdx.x;
    const int t = threadIdx.x;
    const int coct = t & 31, msub = t >> 5;
    const bf16* p = St + (size_t)b * 2048 * 2048
                  + (size_t)(mp * 256 + msub) * 2048 + cb * 256 + coct * 8;
    float s[8] = {};
    for (int i = 0; i < 32; ++i) {
        union { uint4 u; unsigned short h[8]; } cv;
        cv.u = *(const uint4*)(p + (size_t)i * 8 * 2048);
        #pragma unroll
        for (int j = 0; j < 8; ++j) s[j] += __expf(bf2f_bits(cv.h[j]));
    }
    __shared__ float red[256][8];
    #pragma unroll
    for (int j = 0; j < 8; ++j) red[t][j] = s[j];
    __syncthreads();
    if (t < 32) {
        #pragma unroll
        for (int j = 0; j < 8; ++j) {
            float tot = 0.f;
            #pragma unroll
            for (int ms = 0; ms < 8; ++ms) tot += red[ms * 32 + t][j];
            atomicAdd(&Z[b * 2048 + cb * 256 + t * 8 + j], tot);
        }
    }
}

// P2: St[m][l] = exp(St[m][l]) / Z[l]
__global__ __launch_bounds__(256)
void softmax_norm(bf16* __restrict__ St, const float* __restrict__ Z)
{
    const int b = blockIdx.z, mp = blockIdx.y, cb = blockIdx.x;
    const int t = threadIdx.x;
    const int coct = t & 31, msub = t >> 5;
    bf16* p = St + (size_t)b * 2048 * 2048
            + (size_t)(mp * 256 + msub) * 2048 + cb * 256 + coct * 8;
    float iz[8];
    #pragma unroll
    for (int j = 0; j < 8; ++j) iz[j] = 1.0f / Z[b * 2048 + cb * 256 + coct * 8 + j];
    for (int i = 0; i < 32; ++i) {
        union { uint4 u; unsigned short h[8]; } cv;
        cv.u = *(const uint4*)(p + (size_t)i * 8 * 2048);
        #pragma unroll
        for (int j = 0; j < 8; ++j) cv.h[j] = f2bf_bits(__expf(bf2f_bits(cv.h[j])) * iz[j]);
        *(uint4*)(p + (size_t)i * 8 * 2048) = cv.u;
    }
}

extern "C" void kernel_launch(void* const* d_in, const int* in_sizes, int n_in,
                              void* d_out, int out_size, void* d_ws, size_t ws_size,
                              hipStream_t stream)
{
    const int Bb = 8, Cc = 1024, Ll = 2048, Aa = 128;
    const float* x  = (const float*)d_in[0];
    const float* Wk = (const float*)d_in[1];
    const float* bk = (const float*)d_in[2];
    const float* Wq = (const float*)d_in[3];
    const float* bq = (const float*)d_in[4];
    const float* Wp = (const float*)d_in[5];
    const float* bp = (const float*)d_in[6];
    float* out = (float*)d_out;

    const float kscale = 2.0f / (float)Ll;     // softmax(values/(L/2)), folded into K-proj
    const size_t nX = (size_t)Bb * Cc * Ll;    // 16,777,216

    // workspace (bf16 elems): xb | xt(=O1t later) | KQt | Wkqb | Wpb | St
    bf16* xb   = (bf16*)d_ws;
    bf16* xt   = xb + nX;                       // dead after stage12 -> O1t
    bf16* KQt  = xt + nX;                       // [b][l][256]; dead after stage3 -> Z
    bf16* Wkqb = KQt + (size_t)Bb * Ll * 256;
    bf16* Wpb  = Wkqb + (size_t)256 * Cc;
    bf16* St   = Wpb + (size_t)Cc * Cc;         // [b][m][l]
    bf16* O1t  = xt;                            // [b][m][c]
    float* Z   = (float*)KQt;                   // [b][l] fp32 (64 KB)
    float* scl = (float*)St;                    // aliases St: used only in stage12 epilogue
    float* b2  = scl + 256;

    dim3 blk(256, 1, 1);

    // --- prep: biases, weights, x convert+transpose ---
    prep_bias<<<dim3(1), blk, 0, stream>>>(bk, bq, scl, b2, kscale);
    f32_to_bf16<<<dim3(Aa * Cc / 8 / 256), blk, 0, stream>>>(Wk, Wkqb, Aa * Cc / 8);
    f32_to_bf16<<<dim3(Aa * Cc / 8 / 256), blk, 0, stream>>>(Wq, Wkqb + (size_t)Aa * Cc, Aa * Cc / 8);
    f32_to_bf16<<<dim3(Cc * Cc / 8 / 256), blk, 0, stream>>>(Wp, Wpb, Cc * Cc / 8);
    conv_x<<<dim3(Ll / 64, Cc / 64, Bb), blk, 0, stream>>>(x, xb, xt);

    // --- stage 1+2: KQt[b][l][0:128]=K (scaled), [128:256]=Q ---
    gemm128<1, false><<<dim3(2, Ll / 128, Bb), blk, 0, stream>>>(
        xt, (long)Ll * Cc, Cc,   Wkqb, 0, Cc,
        KQt, (long)Ll * 256, 256,  scl, b2, Cc);

    // --- stage 3: St[b][m][l] = sum_a Q[m,a] K[l,a] ---
    gemm128<0, false><<<dim3(Ll / 128, Ll / 128, Bb), blk, 0, stream>>>(
        KQt + 128, (long)Ll * 256, 256,   KQt, (long)Ll * 256, 256,
        St, (long)Ll * Ll, Ll,  nullptr, nullptr, Aa);

    // --- softmax over m (columns of St) ---
    hipMemsetAsync(Z, 0, (size_t)Bb * Ll * sizeof(float), stream);  // KQt dead now
    softmax_sum <<<dim3(Ll / 256, Ll / 256, Bb), blk, 0, stream>>>(St, Z);
    softmax_norm<<<dim3(Ll / 256, Ll / 256, Bb), blk, 0, stream>>>(St, Z);

    // --- stage 5: O1t[b][m][c] = sum_l attn[l,m] x[c,l] ---
    gemm128<0, false><<<dim3(Cc / 128, Ll / 128, Bb), blk, 0, stream>>>(
        St, (long)Ll * Ll, Ll,   xb, (long)Cc * Ll, Ll,
        O1t, (long)Ll * Cc, Cc,  nullptr, nullptr, Ll);

    // --- stage 6: out[b][d][m] = sum_c Wp[d,c] O1t[m,c] + bp[d]  (fp32 out) ---
    gemm128<2, true><<<dim3(Ll / 128, Cc / 128, Bb), blk, 0, stream>>>(
        Wpb, 0, Cc,   O1t, (long)Ll * Cc, Cc,
        out, (long)Cc * Ll, Ll,  bp, nullptr, Cc);
}

// Round 4
// 312.177 us; speedup vs baseline: 3.4608x; 1.1805x over previous
//
#include <hip/hip_runtime.h>
#include <hip/hip_bf16.h>

typedef __hip_bfloat16 bf16;
typedef __attribute__((ext_vector_type(8))) short bfrag8;   // 8 bf16 = 4 VGPRs
typedef __attribute__((ext_vector_type(4))) float floatx4;  // MFMA C/D frag

__device__ inline float bf2f_bits(unsigned short u) {
    unsigned int b = (unsigned int)u << 16;
    float f; __builtin_memcpy(&f, &b, 4); return f;
}
__device__ inline unsigned short f2bf_bits(float f) {
    union { __hip_bfloat16 h; unsigned short u; } c;
    c.h = __float2bfloat16(f);
    return c.u;
}

// async global->LDS, 16B per lane. LDS dest MUST be wave-uniform base + lane*16.
__device__ __forceinline__ void async_copy16(const bf16* g, unsigned short* lds) {
    __builtin_amdgcn_global_load_lds(
        (const __attribute__((address_space(1))) unsigned int*)g,
        (__attribute__((address_space(3))) unsigned int*)lds, 16, 0, 0);
}

// ---------------------------------------------------------------------------
// Uniform GEMM: out[rowA][rowB] = sum_k A[rowA][k] * B[rowB][k]
// Both operands K-contiguous. 128x128 tile, BK=64, 4 waves, 4x4 acc each.
// 1D grid, XCD-aware decode: batch = blockIdx.x & 7 (one batch per XCD under
// the %8 round-robin heuristic — perf-only assumption). MFAST picks which of
// mT/nT is the fast-varying index (L2 strip-reuse control).
// BIASMODE: 0 none; 1 col: v=v*scl[col]+b2[col]; 2 row: v+=scl[row].
// EXPZ: v=exp(v) before store; Z[l=col] += column sums (shfl + atomicAdd).
// ---------------------------------------------------------------------------
template<int BIASMODE, bool OUTF32, bool EXPZ, bool MFAST>
__global__ __launch_bounds__(256)
void gemm128(const bf16* __restrict__ Ag, long sAb, int lda,
             const bf16* __restrict__ Bg, long sBb, int ldb,
             void* __restrict__ Cg, long sCb, int ldc,
             const float* __restrict__ scl, const float* __restrict__ b2,
             float* __restrict__ Zp, int K, int logfast)
{
    __shared__ unsigned short As[128 * 64];
    __shared__ unsigned short Bs[128 * 64];

    const int lin = blockIdx.x;
    const int bz  = lin & 7;
    const int s   = lin >> 3;
    const int msk = (1 << logfast) - 1;
    int mT, nT;
    if (MFAST) { mT = s & msk; nT = s >> logfast; }
    else       { nT = s & msk; mT = s >> logfast; }

    const bf16* A  = Ag + (size_t)bz * sAb + (size_t)mT * 128 * lda;
    const bf16* Bp = Bg + (size_t)bz * sBb + (size_t)nT * 128 * ldb;
    const int t    = threadIdx.x;
    const int wave = t >> 6;
    const int lane = t & 63;
    const int qrow = lane & 15;
    const int quad = lane >> 4;
    const int wr = (wave >> 1) * 64;   // wave's 64x64 quadrant
    const int wc = (wave & 1) * 64;

    floatx4 acc[4][4] = {};

    for (int k0 = 0; k0 < K; k0 += 64) {
        #pragma unroll
        for (int j = 0; j < 4; ++j) {           // A tile: 1024 chunks of 16B
            int c = j * 256 + t;
            int r = c >> 3, p = c & 7;
            int g = p ^ (r & 7);                // XOR swizzle on source addr
            async_copy16(A + (size_t)r * lda + k0 + g * 8, &As[c * 8]);
        }
        #pragma unroll
        for (int j = 0; j < 4; ++j) {           // B tile
            int c = j * 256 + t;
            int r = c >> 3, p = c & 7;
            int g = p ^ (r & 7);
            async_copy16(Bp + (size_t)r * ldb + k0 + g * 8, &Bs[c * 8]);
        }
        __syncthreads();                        // drains vmcnt (global_load_lds)

        #pragma unroll
        for (int ks = 0; ks < 2; ++ks) {
            bfrag8 af[4], bfv[4];
            #pragma unroll
            for (int mi = 0; mi < 4; ++mi) {
                int row = wr + mi * 16 + qrow;
                int ck  = ks * 4 + quad;
                af[mi] = *(const bfrag8*)&As[row * 64 + ((ck ^ (row & 7)) * 8)];
            }
            #pragma unroll
            for (int ni = 0; ni < 4; ++ni) {
                int row = wc + ni * 16 + qrow;
                int ck  = ks * 4 + quad;
                bfv[ni] = *(const bfrag8*)&Bs[row * 64 + ((ck ^ (row & 7)) * 8)];
            }
            #pragma unroll
            for (int mi = 0; mi < 4; ++mi)
                #pragma unroll
                for (int ni = 0; ni < 4; ++ni)
                    acc[mi][ni] = __builtin_amdgcn_mfma_f32_16x16x32_bf16(
                        af[mi], bfv[ni], acc[mi][ni], 0, 0, 0);
        }
        __syncthreads();
    }

    // epilogue: D layout col=lane&15, row=quad*4+reg  [m89-verified]
    const int bmr = mT * 128 + wr;
    const int bnc = nT * 128 + wc;
    float zp[4] = {0.f, 0.f, 0.f, 0.f};
    #pragma unroll
    for (int mi = 0; mi < 4; ++mi) {
        #pragma unroll
        for (int ni = 0; ni < 4; ++ni) {
            int col = bnc + ni * 16 + qrow;
            #pragma unroll
            for (int r = 0; r < 4; ++r) {
                int row = bmr + mi * 16 + quad * 4 + r;
                float v = acc[mi][ni][r];
                if (EXPZ) { v = __expf(v); zp[ni] += v; }
                if (BIASMODE == 1) v = v * scl[col] + b2[col];
                if (BIASMODE == 2) v += scl[row];
                if (OUTF32)
                    ((float*)Cg + (size_t)bz * sCb)[(size_t)row * ldc + col] = v;
                else
                    ((bf16*)Cg + (size_t)bz * sCb)[(size_t)row * ldc + col] = __float2bfloat16(v);
            }
        }
    }
    if (EXPZ) {
        #pragma unroll
        for (int ni = 0; ni < 4; ++ni) {
            float tt = zp[ni];
            tt += __shfl_xor(tt, 16, 64);   // combine quad bit0
            tt += __shfl_xor(tt, 32, 64);   // combine quad bit1
            if (quad == 0)
                atomicAdd(&Zp[bz * 2048 + bnc + ni * 16 + qrow], tt);
        }
    }
}

// Convert Wk, Wq -> Wkqb (concat, 256 rows) and Wp -> Wpb. 8 elems/thread.
__global__ __launch_bounds__(256)
void conv_w(const float* __restrict__ Wk, const float* __restrict__ Wq,
            const float* __restrict__ Wp, bf16* __restrict__ Wkqb,
            bf16* __restrict__ Wpb)
{
    const int nW8 = 131072 / 8;   // 16384
    int i = blockIdx.x * 256 + threadIdx.x;   // 640 blocks -> 163840 threads
    const float* src; bf16* dst; int off;
    if (i < nW8)            { src = Wk; dst = Wkqb;          off = i; }
    else if (i < 2 * nW8)   { src = Wq; dst = Wkqb + 131072; off = i - nW8; }
    else                    { src = Wp; dst = Wpb;           off = i - 2 * nW8; }
    const float4* sp = (const float4*)(src) + off * 2;
    float4 a = sp[0], b = sp[1];
    union { uint4 u; unsigned short h[8]; } o;
    o.h[0] = f2bf_bits(a.x); o.h[1] = f2bf_bits(a.y);
    o.h[2] = f2bf_bits(a.z); o.h[3] = f2bf_bits(a.w);
    o.h[4] = f2bf_bits(b.x); o.h[5] = f2bf_bits(b.y);
    o.h[6] = f2bf_bits(b.z); o.h[7] = f2bf_bits(b.w);
    ((uint4*)dst)[off] = o.u;
}

// x fp32 [C,L] -> xt bf16 [L,C]   (64x64 LDS tile transpose)
__global__ __launch_bounds__(256)
void conv_x(const float* __restrict__ x, bf16* __restrict__ xt)
{
    const int b = blockIdx.z;
    const int l0 = blockIdx.x * 64, c0 = blockIdx.y * 64;
    const float* xp = x + (size_t)b * 1024 * 2048;
    bf16* xtp = xt + (size_t)b * 2048 * 1024;
    __shared__ unsigned short tile[64][65];
    const int t = threadIdx.x;
    const int tr = t >> 4, tc4 = (t & 15) * 4;
    #pragma unroll
    for (int i = 0; i < 4; ++i) {
        int r = i * 16 + tr;   // local c
        float4 v = *(const float4*)(xp + (size_t)(c0 + r) * 2048 + l0 + tc4);
        tile[r][tc4]     = f2bf_bits(v.x);
        tile[r][tc4 + 1] = f2bf_bits(v.y);
        tile[r][tc4 + 2] = f2bf_bits(v.z);
        tile[r][tc4 + 3] = f2bf_bits(v.w);
    }
    __syncthreads();
    #pragma unroll
    for (int i = 0; i < 4; ++i) {
        int lrow = i * 16 + tr;   // local l
        union { uint2 u; unsigned short h[4]; } o;
        #pragma unroll
        for (int j = 0; j < 4; ++j) o.h[j] = tile[tc4 + j][lrow];
        *(uint2*)(xtp + (size_t)(l0 + lrow) * 1024 + c0 + tc4) = o.u;
    }
}

// col-bias prep: scl[i] = (i<128 ? kscale : 1); b2[i] = bias_i * scl[i]
__global__ void prep_bias(const float* __restrict__ bk, const float* __restrict__ bq,
                          float* __restrict__ scl, float* __restrict__ b2, float kscale)
{
    int t = threadIdx.x;   // 256
    float s = (t < 128) ? kscale : 1.0f;
    scl[t] = s;
    b2[t] = ((t < 128) ? bk[t] : bq[t - 128]) * s;
}

// xs[b][c][l] = bf16( x[b][c][l] / Z[b][l] ).  8 elems/thread, fp32 source.
__global__ __launch_bounds__(256)
void normx(const float* __restrict__ x, const float* __restrict__ Z,
           bf16* __restrict__ xs)
{
    size_t i = (size_t)blockIdx.x * 256 + threadIdx.x;
    size_t flat = i * 8;
    int l = (int)(flat & 2047);
    int b = (int)(flat >> 21);          // 2^21 = C*L
    const float* zr = Z + b * 2048 + l;
    const float4* sp = (const float4*)(x + flat);
    float4 a = sp[0], c = sp[1];
    union { uint4 u; unsigned short h[8]; } o;
    o.h[0] = f2bf_bits(a.x / zr[0]); o.h[1] = f2bf_bits(a.y / zr[1]);
    o.h[2] = f2bf_bits(a.z / zr[2]); o.h[3] = f2bf_bits(a.w / zr[3]);
    o.h[4] = f2bf_bits(c.x / zr[4]); o.h[5] = f2bf_bits(c.y / zr[5]);
    o.h[6] = f2bf_bits(c.z / zr[6]); o.h[7] = f2bf_bits(c.w / zr[7]);
    ((uint4*)(xs))[i] = o.u;
}

extern "C" void kernel_launch(void* const* d_in, const int* in_sizes, int n_in,
                              void* d_out, int out_size, void* d_ws, size_t ws_size,
                              hipStream_t stream)
{
    const int Cc = 1024, Ll = 2048, Aa = 128;
    const float* x  = (const float*)d_in[0];
    const float* Wk = (const float*)d_in[1];
    const float* bk = (const float*)d_in[2];
    const float* Wq = (const float*)d_in[3];
    const float* bq = (const float*)d_in[4];
    const float* Wp = (const float*)d_in[5];
    const float* bp = (const float*)d_in[6];
    float* out = (float*)d_out;

    const float kscale = 2.0f / (float)Ll;     // softmax(values/(L/2)) folded into K
    const size_t nX = (size_t)8 * Cc * Ll;     // 16,777,216 elems

    // ws layout (bf16 elems) — total 145,227,776 B, identical to round-3 footprint:
    // xt | KQt | Wkqb | Wpb | St | xs ;  O1t aliases xt (dead after stage12),
    // Z aliases Wkqb (dead after stage12), scl/b2 alias St (read before stage3 writes).
    bf16* xt   = (bf16*)d_ws;                          // [b][l][c]
    bf16* KQt  = xt + nX;                              // [b][l][256]
    bf16* Wkqb = KQt + (size_t)8 * Ll * 256;           // [256][C]
    bf16* Wpb  = Wkqb + (size_t)256 * Cc;              // [C][C]
    bf16* St   = Wpb + (size_t)Cc * Cc;                // [b][m][l]  (holds E=exp)
    bf16* xs   = St + (size_t)8 * Ll * Ll;             // [b][c][l]
    bf16* O1t  = xt;                                   // [b][m][c]
    float* Z   = (float*)Wkqb;                         // [b][l] fp32 (64 KB)
    float* scl = (float*)St;
    float* b2  = scl + 256;

    dim3 blk(256, 1, 1);

    prep_bias<<<dim3(1), blk, 0, stream>>>(bk, bq, scl, b2, kscale);
    conv_w<<<dim3(640), blk, 0, stream>>>(Wk, Wq, Wp, Wkqb, Wpb);
    conv_x<<<dim3(Ll / 64, Cc / 64, 8), blk, 0, stream>>>(x, xt);

    // stage 1+2: KQt[b][l][0:128]=K*kscale, [128:256]=Q.  M=l(16T), N=256(2T)
    gemm128<1, false, false, false><<<dim3(8 * 16 * 2), blk, 0, stream>>>(
        xt, (long)Ll * Cc, Cc,   Wkqb, 0, Cc,
        KQt, (long)Ll * 256, 256,  scl, b2, nullptr, Cc, 1);

    // Z = 0 (aliases Wkqb — dead after stage12)
    hipMemsetAsync(Z, 0, (size_t)8 * Ll * sizeof(float), stream);

    // stage 3: St[b][m][l] = exp(sum_a Q[m,a] K[l,a]);  Z[l] += col sums.
    gemm128<0, false, true, false><<<dim3(8 * 16 * 16), blk, 0, stream>>>(
        KQt + 128, (long)Ll * 256, 256,   KQt, (long)Ll * 256, 256,
        St, (long)Ll * Ll, Ll,  nullptr, nullptr, Z, Aa, 4);

    // xs = x / Z[l]   (folds softmax normalization onto the x operand)
    normx<<<dim3(nX / 8 / 256), blk, 0, stream>>>(x, Z, xs);

    // stage 5: O1t[b][m][c] = sum_l E[m,l] xs[c,l].  M=m(16T), N=c(8T)
    gemm128<0, false, false, false><<<dim3(8 * 16 * 8), blk, 0, stream>>>(
        St, (long)Ll * Ll, Ll,   xs, (long)Cc * Ll, Ll,
        O1t, (long)Ll * Cc, Cc,  nullptr, nullptr, nullptr, Ll, 3);

    // stage 6: out[b][d][m] = sum_c Wp[d,c] O1t[m,c] + bp[d]  (fp32 out)
    // MFAST: d-tiles fastest -> Wp (2 MB) becomes L2-resident per XCD.
    gemm128<2, true, false, true><<<dim3(8 * 8 * 16), blk, 0, stream>>>(
        Wpb, 0, Cc,   O1t, (long)Ll * Cc, Cc,
        out, (long)Cc * Ll, Ll,  bp, nullptr, nullptr, Cc, 3);
}

// Round 6
// 276.553 us; speedup vs baseline: 3.9066x; 1.1288x over previous
//
#include <hip/hip_runtime.h>
#include <hip/hip_bf16.h>

typedef __hip_bfloat16 bf16;
typedef __attribute__((ext_vector_type(8))) short bfrag8;   // 8 bf16 (MFMA A/B frag)
typedef __attribute__((ext_vector_type(8))) int intx8;      // 32 fp8 bytes (MX frag)
typedef __attribute__((ext_vector_type(4))) float floatx4;  // MFMA C/D frag

// Scale ladder (powers of 2, folded exactly in fp32 epilogues):
//   Wp8 = Wp*2^11 ; St8 = (exp(v)-1)*2^12 ; xs8 = (x/Z)*2^16
//   Dlt = acc5*2^-10 (= Delta*2^18) ; out = acc6*2^-29 + base[d]

__device__ __forceinline__ unsigned char f2fp8(float f) {
    f = fminf(fmaxf(f, -448.f), 448.f);            // clamp: overflow->NaN is the r5 killer
    return (unsigned char)(__builtin_amdgcn_cvt_pk_fp8_f32(f, f, 0, false) & 0xFF);
}

__device__ __forceinline__ void async_copy16(const void* g, void* lds) {
    __builtin_amdgcn_global_load_lds(
        (const __attribute__((address_space(1))) unsigned int*)g,
        (__attribute__((address_space(3))) unsigned int*)lds, 16, 0, 0);
}

// ---------------------------------------------------------------------------
// bf16 GEMM (PROVEN round-4 core): out[rowA][rowB] = sum_k A[rowA][k]*B[rowB][k]
// OUTKIND: 0 bf16, 1 f32, 2 fp8 of (exp-1)*4096 (with EXPZ).
// ---------------------------------------------------------------------------
template<int BIASMODE, int OUTKIND, bool EXPZ, bool MFAST>
__global__ __launch_bounds__(256)
void gemm128(const bf16* __restrict__ Ag, long sAb, int lda,
             const bf16* __restrict__ Bg, long sBb, int ldb,
             void* __restrict__ Cg, long sCb, int ldc,
             const float* __restrict__ scl, const float* __restrict__ b2,
             float* __restrict__ Zp, int K, int logfast)
{
    __shared__ unsigned short As[128 * 64];
    __shared__ unsigned short Bs[128 * 64];

    const int lin = blockIdx.x;
    const int bz  = lin & 7;              // XCD-aware: one batch per XCD
    const int s   = lin >> 3;
    const int msk = (1 << logfast) - 1;
    int mT, nT;
    if (MFAST) { mT = s & msk; nT = s >> logfast; }
    else       { nT = s & msk; mT = s >> logfast; }

    const bf16* A  = Ag + (size_t)bz * sAb + (size_t)mT * 128 * lda;
    const bf16* Bp = Bg + (size_t)bz * sBb + (size_t)nT * 128 * ldb;
    const int t = threadIdx.x, wave = t >> 6, lane = t & 63;
    const int qrow = lane & 15, quad = lane >> 4;
    const int wr = (wave >> 1) * 64, wc = (wave & 1) * 64;

    floatx4 acc[4][4] = {};

    for (int k0 = 0; k0 < K; k0 += 64) {
        #pragma unroll
        for (int j = 0; j < 4; ++j) {
            int c = j * 256 + t;
            int r = c >> 3, p = c & 7;
            int g = p ^ (r & 7);
            async_copy16(A + (size_t)r * lda + k0 + g * 8, &As[c * 8]);
        }
        #pragma unroll
        for (int j = 0; j < 4; ++j) {
            int c = j * 256 + t;
            int r = c >> 3, p = c & 7;
            int g = p ^ (r & 7);
            async_copy16(Bp + (size_t)r * ldb + k0 + g * 8, &Bs[c * 8]);
        }
        __syncthreads();

        #pragma unroll
        for (int ks = 0; ks < 2; ++ks) {
            bfrag8 af[4], bfv[4];
            #pragma unroll
            for (int mi = 0; mi < 4; ++mi) {
                int row = wr + mi * 16 + qrow;
                int ck  = ks * 4 + quad;
                af[mi] = *(const bfrag8*)&As[row * 64 + ((ck ^ (row & 7)) * 8)];
            }
            #pragma unroll
            for (int ni = 0; ni < 4; ++ni) {
                int row = wc + ni * 16 + qrow;
                int ck  = ks * 4 + quad;
                bfv[ni] = *(const bfrag8*)&Bs[row * 64 + ((ck ^ (row & 7)) * 8)];
            }
            #pragma unroll
            for (int mi = 0; mi < 4; ++mi)
                #pragma unroll
                for (int ni = 0; ni < 4; ++ni)
                    acc[mi][ni] = __builtin_amdgcn_mfma_f32_16x16x32_bf16(
                        af[mi], bfv[ni], acc[mi][ni], 0, 0, 0);
        }
        __syncthreads();
    }

    // D layout: col=lane&15, row=quad*4+reg  [m89-verified]
    const int bmr = mT * 128 + wr, bnc = nT * 128 + wc;
    float zp[4] = {0.f, 0.f, 0.f, 0.f};
    #pragma unroll
    for (int mi = 0; mi < 4; ++mi) {
        #pragma unroll
        for (int ni = 0; ni < 4; ++ni) {
            int col = bnc + ni * 16 + qrow;
            #pragma unroll
            for (int r = 0; r < 4; ++r) {
                int row = bmr + mi * 16 + quad * 4 + r;
                float v = acc[mi][ni][r];
                if (EXPZ) { float e = __expf(v); zp[ni] += e; v = (e - 1.0f) * 4096.0f; }
                if (BIASMODE == 1) v = v * scl[col] + b2[col];
                if (BIASMODE == 2) v += scl[row];
                if (OUTKIND == 1)
                    ((float*)Cg + (size_t)bz * sCb)[(size_t)row * ldc + col] = v;
                else if (OUTKIND == 0)
                    ((bf16*)Cg + (size_t)bz * sCb)[(size_t)row * ldc + col] = __float2bfloat16(v);
                else
                    ((unsigned char*)Cg + (size_t)bz * sCb)[(size_t)row * ldc + col] = f2fp8(v);
            }
        }
    }
    if (EXPZ) {
        #pragma unroll
        for (int ni = 0; ni < 4; ++ni) {
            float tt = zp[ni];
            tt += __shfl_xor(tt, 16, 64);
            tt += __shfl_xor(tt, 32, 64);
            if (quad == 0)
                atomicAdd(&Zp[bz * 2048 + bnc + ni * 16 + qrow], tt);
        }
    }
}

// ---------------------------------------------------------------------------
// fp8 MX GEMM (stages 5/6 only). 128x128 tile, BK=128 bytes, same swizzle.
// MODE 0: fp8 out, v=acc*os.  MODE 2: f32 out, v=acc*os + rowb[bz*1024+row].
// ---------------------------------------------------------------------------
template<int MODE, bool MFAST>
__global__ __launch_bounds__(256)
void gemm_f8(const unsigned char* __restrict__ Ag, long sAb, int lda,
             const unsigned char* __restrict__ Bg, long sBb, int ldb,
             void* __restrict__ Cg, long sCb, int ldc,
             const float* __restrict__ rowb, float os, int K, int logfast)
{
    __shared__ unsigned char As[128 * 128];
    __shared__ unsigned char Bs[128 * 128];

    const int lin = blockIdx.x;
    const int bz  = lin & 7;
    const int s   = lin >> 3;
    const int msk = (1 << logfast) - 1;
    int mT, nT;
    if (MFAST) { mT = s & msk; nT = s >> logfast; }
    else       { nT = s & msk; mT = s >> logfast; }

    const unsigned char* A  = Ag + (size_t)bz * sAb + (size_t)mT * 128 * lda;
    const unsigned char* Bp = Bg + (size_t)bz * sBb + (size_t)nT * 128 * ldb;
    const int t = threadIdx.x, wave = t >> 6, lane = t & 63;
    const int qrow = lane & 15, quad = lane >> 4;
    const int wr = (wave >> 1) * 64, wc = (wave & 1) * 64;

    floatx4 acc[4][4] = {};

    for (int k0 = 0; k0 < K; k0 += 128) {
        #pragma unroll
        for (int j = 0; j < 4; ++j) {
            int c = j * 256 + t;
            int r = c >> 3, p = c & 7;
            int g = p ^ (r & 7);
            async_copy16(A + (size_t)r * lda + k0 + g * 16, &As[c * 16]);
        }
        #pragma unroll
        for (int j = 0; j < 4; ++j) {
            int c = j * 256 + t;
            int r = c >> 3, p = c & 7;
            int g = p ^ (r & 7);
            async_copy16(Bp + (size_t)r * ldb + k0 + g * 16, &Bs[c * 16]);
        }
        __syncthreads();

        intx8 af[4], bf[4];
        #pragma unroll
        for (int mi = 0; mi < 4; ++mi) {
            int row = wr + mi * 16 + qrow, sw = row & 7;
            union { intx8 v; uint4 q[2]; } u;
            u.q[0] = *(const uint4*)&As[row * 128 + (((quad * 2    ) ^ sw) * 16)];
            u.q[1] = *(const uint4*)&As[row * 128 + (((quad * 2 + 1) ^ sw) * 16)];
            af[mi] = u.v;
        }
        #pragma unroll
        for (int ni = 0; ni < 4; ++ni) {
            int row = wc + ni * 16 + qrow, sw = row & 7;
            union { intx8 v; uint4 q[2]; } u;
            u.q[0] = *(const uint4*)&Bs[row * 128 + (((quad * 2    ) ^ sw) * 16)];
            u.q[1] = *(const uint4*)&Bs[row * 128 + (((quad * 2 + 1) ^ sw) * 16)];
            bf[ni] = u.v;
        }
        #pragma unroll
        for (int mi = 0; mi < 4; ++mi)
            #pragma unroll
            for (int ni = 0; ni < 4; ++ni)
                acc[mi][ni] = __builtin_amdgcn_mfma_scale_f32_16x16x128_f8f6f4(
                    af[mi], bf[ni], acc[mi][ni], 0, 0, 0, 127, 0, 127); // fp8/fp8, scales 1.0
        __syncthreads();
    }

    const int bmr = mT * 128 + wr, bnc = nT * 128 + wc;
    #pragma unroll
    for (int mi = 0; mi < 4; ++mi) {
        int row0 = bmr + mi * 16 + quad * 4;
        float4 rb4;
        if (MODE == 2) rb4 = *(const float4*)&rowb[bz * 1024 + row0];
        #pragma unroll
        for (int ni = 0; ni < 4; ++ni) {
            int col = bnc + ni * 16 + qrow;
            floatx4 a = acc[mi][ni];
            if (MODE == 2) {
                float* Co = (float*)Cg + (size_t)bz * sCb;
                Co[(size_t)(row0 + 0) * ldc + col] = a[0] * os + rb4.x;
                Co[(size_t)(row0 + 1) * ldc + col] = a[1] * os + rb4.y;
                Co[(size_t)(row0 + 2) * ldc + col] = a[2] * os + rb4.z;
                Co[(size_t)(row0 + 3) * ldc + col] = a[3] * os + rb4.w;
            } else {
                unsigned char* C8 = (unsigned char*)Cg + (size_t)bz * sCb;
                #pragma unroll
                for (int r = 0; r < 4; ++r)
                    C8[(size_t)(row0 + r) * ldc + col] = f2fp8(a[r] * os);
            }
        }
    }
}

// Wk,Wq -> Wkqb bf16 (concat 256 rows); Wp -> Wp8 fp8 (*2^11). 8 elems/thread.
__global__ __launch_bounds__(256)
void conv_w(const float* __restrict__ Wk, const float* __restrict__ Wq,
            const float* __restrict__ Wp, bf16* __restrict__ Wkqb,
            unsigned char* __restrict__ Wp8)
{
    int i = blockIdx.x * 256 + threadIdx.x;   // 640 blocks
    if (i < 32768) {
        const float* src = (i < 16384) ? Wk : Wq;
        int off = (i < 16384) ? i : i - 16384;
        bf16* dst = Wkqb + (size_t)((i < 16384) ? 0 : 131072);
        const float4* sp = (const float4*)src + (size_t)off * 2;
        float4 a = sp[0], b = sp[1];
        union { uint4 u; unsigned short h[8]; } o;
        union { bf16 h; unsigned short u; } cv;
        cv.h = __float2bfloat16(a.x); o.h[0] = cv.u;
        cv.h = __float2bfloat16(a.y); o.h[1] = cv.u;
        cv.h = __float2bfloat16(a.z); o.h[2] = cv.u;
        cv.h = __float2bfloat16(a.w); o.h[3] = cv.u;
        cv.h = __float2bfloat16(b.x); o.h[4] = cv.u;
        cv.h = __float2bfloat16(b.y); o.h[5] = cv.u;
        cv.h = __float2bfloat16(b.z); o.h[6] = cv.u;
        cv.h = __float2bfloat16(b.w); o.h[7] = cv.u;
        ((uint4*)dst)[off] = o.u;
    } else {
        int off = i - 32768;   // Wp: 131072 chunks
        const float4* sp = (const float4*)Wp + (size_t)off * 2;
        float4 a = sp[0], b = sp[1];
        unsigned char o[8];
        o[0] = f2fp8(a.x * 2048.f); o[1] = f2fp8(a.y * 2048.f);
        o[2] = f2fp8(a.z * 2048.f); o[3] = f2fp8(a.w * 2048.f);
        o[4] = f2fp8(b.x * 2048.f); o[5] = f2fp8(b.y * 2048.f);
        o[6] = f2fp8(b.z * 2048.f); o[7] = f2fp8(b.w * 2048.f);
        uint2 w;
        w.x = (unsigned int)o[0] | ((unsigned int)o[1] << 8) | ((unsigned int)o[2] << 16) | ((unsigned int)o[3] << 24);
        w.y = (unsigned int)o[4] | ((unsigned int)o[5] << 8) | ((unsigned int)o[6] << 16) | ((unsigned int)o[7] << 24);
        ((uint2*)Wp8)[off] = w;
    }
}

// x fp32 [C,L] -> xt bf16 [L,C]  (round-4 proven transpose)
__global__ __launch_bounds__(256)
void conv_x(const float* __restrict__ x, bf16* __restrict__ xt)
{
    const int b = blockIdx.z;
    const int l0 = blockIdx.x * 64, c0 = blockIdx.y * 64;
    const float* xp = x + (size_t)b * 1024 * 2048;
    bf16* xtp = xt + (size_t)b * 2048 * 1024;
    __shared__ unsigned short tile[64][65];
    const int t = threadIdx.x, tr = t >> 4, tc4 = (t & 15) * 4;
    union { bf16 h; unsigned short u; } cv;
    #pragma unroll
    for (int i = 0; i < 4; ++i) {
        int r = i * 16 + tr;
        float4 v = *(const float4*)(xp + (size_t)(c0 + r) * 2048 + l0 + tc4);
        cv.h = __float2bfloat16(v.x); tile[r][tc4]     = cv.u;
        cv.h = __float2bfloat16(v.y); tile[r][tc4 + 1] = cv.u;
        cv.h = __float2bfloat16(v.z); tile[r][tc4 + 2] = cv.u;
        cv.h = __float2bfloat16(v.w); tile[r][tc4 + 3] = cv.u;
    }
    __syncthreads();
    #pragma unroll
    for (int i = 0; i < 4; ++i) {
        int lr = i * 16 + tr;
        union { uint2 u; unsigned short h[4]; } o;
        #pragma unroll
        for (int j = 0; j < 4; ++j) o.h[j] = tile[tc4 + j][lr];
        *(uint2*)(xtp + (size_t)(l0 + lr) * 1024 + c0 + tc4) = o.u;
    }
}

__global__ void prep_bias(const float* __restrict__ bk, const float* __restrict__ bq,
                          float* __restrict__ scl, float* __restrict__ b2, float kscale)
{
    int t = threadIdx.x;   // 256
    float s = (t < 128) ? kscale : 1.0f;
    scl[t] = s;
    b2[t] = ((t < 128) ? bk[t] : bq[t - 128]) * s;
}

// xs8[b][c][l] = fp8(x/Z * 2^16); colsum[b][c] = sum_l x/Z (exact fp32).
__global__ __launch_bounds__(256)
void normx(const float* __restrict__ x, const float* __restrict__ Z,
           unsigned char* __restrict__ xs, float* __restrict__ colsum)
{
    const int bc = blockIdx.x;            // b*1024 + c
    const int b  = bc >> 10;
    const int t  = threadIdx.x;
    const float* xp = x + (size_t)bc * 2048 + t * 8;
    const float* zp = Z + b * 2048 + t * 8;
    float4 a = ((const float4*)xp)[0], c4 = ((const float4*)xp)[1];
    float4 z0 = ((const float4*)zp)[0], z1 = ((const float4*)zp)[1];
    float v[8];
    v[0] = a.x  / fmaxf(z0.x, 1e-10f); v[1] = a.y / fmaxf(z0.y, 1e-10f);
    v[2] = a.z  / fmaxf(z0.z, 1e-10f); v[3] = a.w / fmaxf(z0.w, 1e-10f);
    v[4] = c4.x / fmaxf(z1.x, 1e-10f); v[5] = c4.y / fmaxf(z1.y, 1e-10f);
    v[6] = c4.z / fmaxf(z1.z, 1e-10f); v[7] = c4.w / fmaxf(z1.w, 1e-10f);
    float s = 0.f;
    unsigned char o[8];
    #pragma unroll
    for (int j = 0; j < 8; ++j) { s += v[j]; o[j] = f2fp8(v[j] * 65536.f); }
    uint2 w;
    w.x = (unsigned int)o[0] | ((unsigned int)o[1] << 8) | ((unsigned int)o[2] << 16) | ((unsigned int)o[3] << 24);
    w.y = (unsigned int)o[4] | ((unsigned int)o[5] << 8) | ((unsigned int)o[6] << 16) | ((unsigned int)o[7] << 24);
    ((uint2*)(xs + (size_t)bc * 2048))[t] = w;
    #pragma unroll
    for (int off = 32; off >= 1; off >>= 1) s += __shfl_xor(s, off, 64);
    __shared__ float red[4];
    if ((t & 63) == 0) red[t >> 6] = s;
    __syncthreads();
    if (t == 0) colsum[bc] = red[0] + red[1] + red[2] + red[3];
}

// base[b][d] = bp[d] + sum_c Wp[d,c]*colsum[b][c]  (exact fp32 path)
__global__ __launch_bounds__(256)
void basek(const float* __restrict__ Wp, const float* __restrict__ colsum,
           const float* __restrict__ bp, float* __restrict__ base)
{
    const int d = blockIdx.x, t = threadIdx.x;
    float4 w = *(const float4*)(Wp + (size_t)d * 1024 + t * 4);
    float pb[8];
    #pragma unroll
    for (int b = 0; b < 8; ++b) {
        float4 cs = *(const float4*)(colsum + b * 1024 + t * 4);
        pb[b] = w.x * cs.x + w.y * cs.y + w.z * cs.z + w.w * cs.w;
    }
    __shared__ float red[8][4];
    #pragma unroll
    for (int b = 0; b < 8; ++b) {
        float s = pb[b];
        #pragma unroll
        for (int off = 32; off >= 1; off >>= 1) s += __shfl_xor(s, off, 64);
        if ((t & 63) == 0) red[b][t >> 6] = s;
    }
    __syncthreads();
    if (t < 8) base[t * 1024 + d] = bp[d] + red[t][0] + red[t][1] + red[t][2] + red[t][3];
}

extern "C" void kernel_launch(void* const* d_in, const int* in_sizes, int n_in,
                              void* d_out, int out_size, void* d_ws, size_t ws_size,
                              hipStream_t stream)
{
    const float* x  = (const float*)d_in[0];
    const float* Wk = (const float*)d_in[1];
    const float* bk = (const float*)d_in[2];
    const float* Wq = (const float*)d_in[3];
    const float* bq = (const float*)d_in[4];
    const float* Wp = (const float*)d_in[5];
    const float* bp = (const float*)d_in[6];
    float* out = (float*)d_out;

    const float kscale = 2.0f / 2048.0f;

    // ws layout: xt bf16 33.5MB (Dlt fp8 16.8MB aliases) | KQt bf16 8.4MB |
    //            Wkqb bf16 0.5MB | Wp8 1MB | St8 33.5MB | xs8 16.8MB | floats
    bf16* xt   = (bf16*)d_ws;
    bf16* KQt  = xt + (size_t)8 * 2048 * 1024;
    bf16* Wkqb = KQt + (size_t)8 * 2048 * 256;
    unsigned char* Wp8 = (unsigned char*)(Wkqb + (size_t)256 * 1024);
    unsigned char* St8 = Wp8 + (size_t)1048576;              // [b][m][l]
    unsigned char* xs8 = St8 + (size_t)8 * 2048 * 2048;      // [b][c][l]
    float* Z      = (float*)(xs8 + (size_t)8 * 1024 * 2048); // [b][2048]
    float* colsum = Z + 8 * 2048;
    float* base   = colsum + 8 * 1024;
    float* scl    = base + 8 * 1024;
    float* b2     = scl + 256;
    unsigned char* Dlt = (unsigned char*)xt;                 // [b][m][c] aliases xt

    dim3 blk(256, 1, 1);

    prep_bias<<<dim3(1), blk, 0, stream>>>(bk, bq, scl, b2, kscale);
    conv_w<<<dim3(640), blk, 0, stream>>>(Wk, Wq, Wp, Wkqb, Wp8);
    conv_x<<<dim3(32, 16, 8), blk, 0, stream>>>(x, xt);

    // stage 1+2 (bf16, proven): KQt[l][0:128]=K*kscale, [128:256]=Q
    gemm128<1, 0, false, false><<<dim3(8 * 16 * 2), blk, 0, stream>>>(
        xt, 2048L * 1024, 1024,  Wkqb, 0, 1024,
        KQt, 2048L * 256, 256,  scl, b2, nullptr, 1024, 1);

    hipMemsetAsync(Z, 0, (size_t)8 * 2048 * sizeof(float), stream);

    // stage 3 (bf16 core, proven; new fp8-d store): St8[m][l] = fp8((exp(v)-1)*2^12);
    // Z[l] += col sums of exp (exact fp32, pre-clamp).
    gemm128<0, 2, true, false><<<dim3(8 * 16 * 16), blk, 0, stream>>>(
        KQt + 128, 2048L * 256, 256,  KQt, 2048L * 256, 256,
        St8, 2048L * 2048, 2048,  nullptr, nullptr, Z, 128, 4);

    normx<<<dim3(8 * 1024), blk, 0, stream>>>(x, Z, xs8, colsum);
    basek<<<dim3(1024), blk, 0, stream>>>(Wp, colsum, bp, base);

    // stage 5 (fp8 MX): Dlt[m][c] = fp8(acc*2^-10); K=2048 bytes
    gemm_f8<0, false><<<dim3(8 * 16 * 8), blk, 0, stream>>>(
        St8, 2048L * 2048, 2048,  xs8, 1024L * 2048, 2048,
        Dlt, 2048L * 1024, 1024,  nullptr, 0.0009765625f, 2048, 3);

    // stage 6 (fp8 MX): out[d][m] = acc*2^-29 + base[b][d]; K=1024 bytes
    gemm_f8<2, true><<<dim3(8 * 8 * 16), blk, 0, stream>>>(
        Wp8, 0, 1024,  Dlt, 2048L * 1024, 1024,
        out, 1024L * 2048, 2048,  base, 1.862645149230957e-9f, 1024, 3);
}